// Round 3
// baseline (155.616 us; speedup 1.0000x reference)
//
#include <hip/hip_runtime.h>
#include <hip/hip_bf16.h>
#include <math.h>

#define NROWS 4096
#define DIM   512
#define NCLS  100
#define MAXP  128
#define TAU_INV 10.0f

using short8 = __attribute__((ext_vector_type(8))) short;
using f32x4  = __attribute__((ext_vector_type(4))) float;

// ---- workspace layout (bytes) ----
#define OFF_FNB  0
#define OFF_NEG  4194304
#define OFF_CNT  (OFF_NEG + 16384)
#define OFF_PV   (OFF_CNT + 16384)
#define OFF_HIST (OFF_PV + 4096*MAXP*4)
#define OFF_NUM  (OFF_HIST + 512)
#define OFF_DONE (OFF_NUM + 4)
#define OFF_PART (OFF_HIST + 768)   // float[64] block partials (no init needed)

#define GLOBAL_AS __attribute__((address_space(1)))
#define LDS_AS    __attribute__((address_space(3)))

__device__ __forceinline__ void gload_lds16(const void* g, void* l) {
    __builtin_amdgcn_global_load_lds((const GLOBAL_AS unsigned int*)g,
                                     (LDS_AS unsigned int*)l, 16, 0, 0);
}

__device__ __forceinline__ unsigned short f32_to_bf16_rn(float x) {
    unsigned int u = __float_as_uint(x);
    unsigned int r = u + 0x7FFFu + ((u >> 16) & 1u);
    return (unsigned short)(r >> 16);
}

// one wave per row: fp32 norm, write bf16 row. Fused: hist atomic (lane 0),
// and zeroing of negsum/poscnt (first 32 blocks).
__global__ void k_norm(const float* __restrict__ feat, const int* __restrict__ tgt,
                       unsigned short* __restrict__ fnb, int* __restrict__ hist,
                       int* __restrict__ zero_base) {
    int tid = threadIdx.x;
    if (blockIdx.x < 32) zero_base[blockIdx.x * 256 + tid] = 0;
    int wid = tid >> 6, l = tid & 63;
    int row = blockIdx.x * 4 + wid;
    if (l == 0) atomicAdd(&hist[tgt[row]], 1);
    const float4* src = (const float4*)(feat + (size_t)row * DIM);
    float4 v0 = src[l * 2];
    float4 v1 = src[l * 2 + 1];
    float ss = v0.x*v0.x + v0.y*v0.y + v0.z*v0.z + v0.w*v0.w
             + v1.x*v1.x + v1.y*v1.y + v1.z*v1.z + v1.w*v1.w;
    #pragma unroll
    for (int m = 1; m < 64; m <<= 1) ss += __shfl_xor(ss, m);
    float rs = rsqrtf(fmaxf(ss, 1e-30f));
    float f[8] = { v0.x*rs, v0.y*rs, v0.z*rs, v0.w*rs,
                   v1.x*rs, v1.y*rs, v1.z*rs, v1.w*rs };
    uint4 o;
    o.x = (unsigned)f32_to_bf16_rn(f[0]) | ((unsigned)f32_to_bf16_rn(f[1]) << 16);
    o.y = (unsigned)f32_to_bf16_rn(f[2]) | ((unsigned)f32_to_bf16_rn(f[3]) << 16);
    o.z = (unsigned)f32_to_bf16_rn(f[4]) | ((unsigned)f32_to_bf16_rn(f[5]) << 16);
    o.w = (unsigned)f32_to_bf16_rn(f[6]) | ((unsigned)f32_to_bf16_rn(f[7]) << 16);
    ((uint4*)fnb)[row * 64 + l] = o;
}

// main: 128x128 tile, 4 waves (2x2), 16x16x32 bf16 MFMA.
// Double-buffered LDS, global_load_lds staging with source-side XOR swizzle,
// one barrier per K-tile. Fused epilogue: exp, class mask, neg-sum, pos scatter.
__global__ __launch_bounds__(256, 2)
void k_main(const unsigned short* __restrict__ fnb, const int* __restrict__ tgt,
            float* __restrict__ negsum, int* __restrict__ poscnt,
            float* __restrict__ posvals)
{
    __shared__ uint4 As4[2][1024];   // [buf][row*8 + cx], chunk = 8 bf16 = 16B
    __shared__ uint4 Bs4[2][1024];
    __shared__ int clsI[128];
    __shared__ int clsJ[128];

    int tid = threadIdx.x;
    int i0 = blockIdx.y * 128, j0 = blockIdx.x * 128;
    if (tid < 128) clsI[tid] = tgt[i0 + tid];
    else           clsJ[tid - 128] = tgt[j0 + (tid - 128)];

    int wid = tid >> 6, l = tid & 63;
    int wr = wid >> 1, wc = wid & 1;

    f32x4 acc[4][4];
    #pragma unroll
    for (int a = 0; a < 4; a++)
        #pragma unroll
        for (int b = 0; b < 4; b++)
            acc[a][b] = (f32x4){0.f, 0.f, 0.f, 0.f};

    const uint4* gA = (const uint4*)fnb;   // row*64 + chunk

    // STAGE: LDS slot (row,cx) receives global chunk c = cx ^ (row&7).
    // gload_lds writes linearly (wave base + lane*16); id = row*8+cx is linear
    // in tid, so per-lane source address carries the swizzle (involution).
    #define STAGE(buf, kt)                                                        \
        _Pragma("unroll")                                                         \
        for (int p = 0; p < 4; p++) {                                             \
            int id = p * 256 + tid;                                               \
            int row = id >> 3, cx = id & 7;                                       \
            int c = cx ^ (row & 7);                                               \
            gload_lds16(&gA[(i0 + row) * 64 + (kt) * 8 + c], &As4[buf][id]);      \
            gload_lds16(&gA[(j0 + row) * 64 + (kt) * 8 + c], &Bs4[buf][id]);      \
        }

    #define COMPUTE(buf)                                                          \
        _Pragma("unroll")                                                         \
        for (int s = 0; s < 2; s++) {                                             \
            short8 af[4], bf[4];                                                  \
            _Pragma("unroll")                                                     \
            for (int mi = 0; mi < 4; mi++) {                                      \
                int row = wr * 64 + mi * 16 + (l & 15);                           \
                int cx = (s * 4 + (l >> 4)) ^ (row & 7);                          \
                af[mi] = *(const short8*)&As4[buf][row * 8 + cx];                 \
            }                                                                     \
            _Pragma("unroll")                                                     \
            for (int ni = 0; ni < 4; ni++) {                                      \
                int row = wc * 64 + ni * 16 + (l & 15);                           \
                int cx = (s * 4 + (l >> 4)) ^ (row & 7);                          \
                bf[ni] = *(const short8*)&Bs4[buf][row * 8 + cx];                 \
            }                                                                     \
            _Pragma("unroll")                                                     \
            for (int mi = 0; mi < 4; mi++)                                        \
                _Pragma("unroll")                                                 \
                for (int ni = 0; ni < 4; ni++)                                    \
                    acc[mi][ni] = __builtin_amdgcn_mfma_f32_16x16x32_bf16(        \
                        af[mi], bf[ni], acc[mi][ni], 0, 0, 0);                    \
        }

    STAGE(0, 0);
    __syncthreads();                 // compiler drains vmcnt before barrier
    int cur = 0;
    for (int kt = 0; kt < 7; kt++) {
        STAGE(cur ^ 1, kt + 1);      // loads fly under this tile's compute
        COMPUTE(cur);
        __syncthreads();             // drains vmcnt+lgkmcnt: next buffer ready
        cur ^= 1;
    }
    COMPUTE(cur);

    // ---- epilogue ----
    int cj[4], gj[4];
    #pragma unroll
    for (int ni = 0; ni < 4; ni++) {
        int jl = wc * 64 + ni * 16 + (l & 15);
        cj[ni] = clsJ[jl];
        gj[ni] = j0 + jl;
    }
    float ns[4][4];
    #pragma unroll
    for (int mi = 0; mi < 4; mi++) {
        #pragma unroll
        for (int r = 0; r < 4; r++) {
            int il = wr * 64 + mi * 16 + ((l >> 4) << 2) + r;
            int ci = clsI[il];
            int gi = i0 + il;
            float nacc = 0.f;
            #pragma unroll
            for (int ni = 0; ni < 4; ni++) {
                float p = acc[mi][ni][r] * TAU_INV;
                float e = __expf(p);
                if (ci != cj[ni]) {
                    nacc += e;
                } else if (gi != gj[ni]) {
                    int slot = atomicAdd(&poscnt[gi], 1);
                    if (slot < MAXP) posvals[(size_t)gi * MAXP + slot] = p;
                }
            }
            ns[mi][r] = nacc;
        }
    }
    #pragma unroll
    for (int mi = 0; mi < 4; mi++) {
        #pragma unroll
        for (int r = 0; r < 4; r++) {
            float v = ns[mi][r];
            v += __shfl_xor(v, 1);
            v += __shfl_xor(v, 2);
            v += __shfl_xor(v, 4);
            v += __shfl_xor(v, 8);
            if ((l & 15) == 0) {
                int il = wr * 64 + mi * 16 + ((l >> 4) << 2) + r;
                atomicAdd(&negsum[i0 + il], v);
            }
        }
    }
    #undef STAGE
    #undef COMPUTE
}

// wave per row (lanes = positives, coalesced); 64 blocks; block partial +
// done-ticket finalize (denominator + divide) in the last block.
__global__ void k_fin(const float* __restrict__ negsum, const int* __restrict__ poscnt,
                      const float* __restrict__ posvals, const int* __restrict__ tgt,
                      const int* __restrict__ hist, float* __restrict__ partial,
                      int* __restrict__ done, float* __restrict__ out)
{
    __shared__ float red[4];
    __shared__ int lastflag;
    int tid = threadIdx.x, w = tid >> 6, l = tid & 63;
    float acc = 0.f;
    int base = (blockIdx.x * 4 + w) * 16;
    for (int it = 0; it < 16; it++) {
        int row = base + it;
        float S = negsum[row];
        int m = poscnt[row]; if (m > MAXP) m = MAXP;
        float t = 0.f;
        if (l < m) {
            float p = posvals[(size_t)row * MAXP + l];
            t = __logf(__expf(p) + S) - p;
        }
        if (m > 64 && l + 64 < m) {
            float p = posvals[(size_t)row * MAXP + l + 64];
            t += __logf(__expf(p) + S) - p;
        }
        #pragma unroll
        for (int msk = 1; msk < 64; msk <<= 1) t += __shfl_xor(t, msk);
        if (l == 0 && m > 0) acc += t / (float)hist[tgt[row]];
    }
    if (l == 0) red[w] = acc;
    __syncthreads();
    if (tid == 0) {
        partial[blockIdx.x] = red[0] + red[1] + red[2] + red[3];
        __threadfence();
        int d = atomicAdd(done, 1);
        lastflag = (d == (int)gridDim.x - 1) ? 1 : 0;
    }
    __syncthreads();
    if (lastflag && tid < 64) {
        __threadfence();
        float nsum = partial[tid];
        long long h1 = (tid < NCLS) ? hist[tid] : 0;
        long long h2 = (tid + 64 < NCLS) ? hist[tid + 64] : 0;
        float d2 = (float)(h1 * h1 + h2 * h2);
        #pragma unroll
        for (int msk = 1; msk < 64; msk <<= 1) {
            nsum += __shfl_xor(nsum, msk);
            d2   += __shfl_xor(d2, msk);
        }
        if (tid == 0) out[0] = nsum / d2;
    }
}

extern "C" void kernel_launch(void* const* d_in, const int* in_sizes, int n_in,
                              void* d_out, int out_size, void* d_ws, size_t ws_size,
                              hipStream_t stream) {
    (void)in_sizes; (void)n_in; (void)out_size; (void)ws_size;
    const float* feat = (const float*)d_in[0];
    const int*   tgt  = (const int*)d_in[1];
    float* out = (float*)d_out;
    char* ws = (char*)d_ws;

    unsigned short* fnb = (unsigned short*)(ws + OFF_FNB);
    float* negsum  = (float*)(ws + OFF_NEG);
    int*   poscnt  = (int*)(ws + OFF_CNT);
    float* posvals = (float*)(ws + OFF_PV);
    int*   hist    = (int*)(ws + OFF_HIST);
    int*   done    = (int*)(ws + OFF_DONE);
    float* partial = (float*)(ws + OFF_PART);

    // hist/num/done must be zero before k_norm's fused hist atomics
    hipMemsetAsync(ws + OFF_HIST, 0, 1024, stream);

    k_norm<<<dim3(1024), dim3(256), 0, stream>>>(feat, tgt, fnb, hist, (int*)(ws + OFF_NEG));
    k_main<<<dim3(32, 32), dim3(256), 0, stream>>>(fnb, tgt, negsum, poscnt, posvals);
    k_fin<<<dim3(64), dim3(256), 0, stream>>>(negsum, poscnt, posvals, tgt, hist, partial, done, out);
}

// Round 4
// 119.426 us; speedup vs baseline: 1.3030x; 1.3030x over previous
//
#include <hip/hip_runtime.h>
#include <hip/hip_bf16.h>
#include <math.h>

#define NROWS 4096
#define DIM   512
#define MAXP  128
#define TAU_INV 10.0f

using short8 = __attribute__((ext_vector_type(8))) short;
using f32x4  = __attribute__((ext_vector_type(4))) float;

// ---- workspace layout (bytes) ----
// fnb  : bf16 normalized features 4 MB
// neg  : float[4096], cnt : int[4096]
// tail : num, den, done (zeroed with neg/cnt by k_norm: 33792 B = 33 blocks x 1 KB)
// pv   : float[4096*128] positive logits
#define OFF_FNB  0
#define OFF_NEG  4194304
#define OFF_CNT  (OFF_NEG + 16384)
#define OFF_TAIL (OFF_CNT + 16384)
#define OFF_NUM  (OFF_TAIL)
#define OFF_DEN  (OFF_TAIL + 4)
#define OFF_DONE (OFF_TAIL + 8)
#define OFF_PV   (OFF_TAIL + 1024)

#define GLOBAL_AS __attribute__((address_space(1)))
#define LDS_AS    __attribute__((address_space(3)))

__device__ __forceinline__ void gload_lds16(const void* g, void* l) {
    __builtin_amdgcn_global_load_lds((const GLOBAL_AS unsigned int*)g,
                                     (LDS_AS unsigned int*)l, 16, 0, 0);
}

__device__ __forceinline__ unsigned short f32_to_bf16_rn(float x) {
    unsigned int u = __float_as_uint(x);
    unsigned int r = u + 0x7FFFu + ((u >> 16) & 1u);
    return (unsigned short)(r >> 16);
}

// one wave per row: fp32 norm -> bf16 row. First 33 blocks zero negsum/poscnt/tail.
__global__ void k_norm(const float* __restrict__ feat,
                       unsigned short* __restrict__ fnb,
                       int* __restrict__ zero_base /* 8448 ints */) {
    int tid = threadIdx.x;
    if (blockIdx.x < 33) zero_base[blockIdx.x * 256 + tid] = 0;
    int wid = tid >> 6, l = tid & 63;
    int row = blockIdx.x * 4 + wid;
    const float4* src = (const float4*)(feat + (size_t)row * DIM);
    float4 v0 = src[l * 2];
    float4 v1 = src[l * 2 + 1];
    float ss = v0.x*v0.x + v0.y*v0.y + v0.z*v0.z + v0.w*v0.w
             + v1.x*v1.x + v1.y*v1.y + v1.z*v1.z + v1.w*v1.w;
    #pragma unroll
    for (int m = 1; m < 64; m <<= 1) ss += __shfl_xor(ss, m);
    float rs = rsqrtf(fmaxf(ss, 1e-30f));
    float f[8] = { v0.x*rs, v0.y*rs, v0.z*rs, v0.w*rs,
                   v1.x*rs, v1.y*rs, v1.z*rs, v1.w*rs };
    uint4 o;
    o.x = (unsigned)f32_to_bf16_rn(f[0]) | ((unsigned)f32_to_bf16_rn(f[1]) << 16);
    o.y = (unsigned)f32_to_bf16_rn(f[2]) | ((unsigned)f32_to_bf16_rn(f[3]) << 16);
    o.z = (unsigned)f32_to_bf16_rn(f[4]) | ((unsigned)f32_to_bf16_rn(f[5]) << 16);
    o.w = (unsigned)f32_to_bf16_rn(f[6]) | ((unsigned)f32_to_bf16_rn(f[7]) << 16);
    ((uint4*)fnb)[row * 64 + l] = o;
}

// main: 128x128 tile, 4 waves (2x2), 16x16x32 bf16 MFMA. m97 structure:
// single LDS buffer, global_load_lds (16B) with source-side XOR swizzle,
// STAGE -> sync -> COMPUTE -> sync. Fused epilogue.
__global__ __launch_bounds__(256, 2)
void k_main(const unsigned short* __restrict__ fnb, const int* __restrict__ tgt,
            float* __restrict__ negsum, int* __restrict__ poscnt,
            float* __restrict__ posvals)
{
    __shared__ uint4 As4[1024];   // [row*8 + cx], chunk = 8 bf16 = 16B
    __shared__ uint4 Bs4[1024];
    __shared__ int clsI[128];
    __shared__ int clsJ[128];

    int tid = threadIdx.x;
    int i0 = blockIdx.y * 128, j0 = blockIdx.x * 128;
    if (tid < 128) clsI[tid] = tgt[i0 + tid];
    else           clsJ[tid - 128] = tgt[j0 + (tid - 128)];

    int wid = tid >> 6, l = tid & 63;
    int wr = wid >> 1, wc = wid & 1;

    f32x4 acc[4][4];
    #pragma unroll
    for (int a = 0; a < 4; a++)
        #pragma unroll
        for (int b = 0; b < 4; b++)
            acc[a][b] = (f32x4){0.f, 0.f, 0.f, 0.f};

    const uint4* gA = (const uint4*)fnb;   // row*64 + chunk

    // LDS slot (row,cx) <- global chunk c = cx ^ (row&7). gload_lds writes
    // linearly (wave base + lane*16); id is linear in tid, so the per-lane
    // SOURCE address carries the swizzle (involution; rule #21).
    for (int kt = 0; kt < 8; kt++) {
        #pragma unroll
        for (int p = 0; p < 4; p++) {
            int id = p * 256 + tid;
            int row = id >> 3, cx = id & 7;
            int c = cx ^ (row & 7);
            gload_lds16(&gA[(i0 + row) * 64 + kt * 8 + c], &As4[id]);
            gload_lds16(&gA[(j0 + row) * 64 + kt * 8 + c], &Bs4[id]);
        }
        __syncthreads();
        #pragma unroll
        for (int s = 0; s < 2; s++) {
            short8 af[4], bf[4];
            #pragma unroll
            for (int mi = 0; mi < 4; mi++) {
                int row = wr * 64 + mi * 16 + (l & 15);
                int cx = (s * 4 + (l >> 4)) ^ (row & 7);
                af[mi] = *(const short8*)&As4[row * 8 + cx];
            }
            #pragma unroll
            for (int ni = 0; ni < 4; ni++) {
                int row = wc * 64 + ni * 16 + (l & 15);
                int cx = (s * 4 + (l >> 4)) ^ (row & 7);
                bf[ni] = *(const short8*)&Bs4[row * 8 + cx];
            }
            #pragma unroll
            for (int mi = 0; mi < 4; mi++)
                #pragma unroll
                for (int ni = 0; ni < 4; ni++)
                    acc[mi][ni] = __builtin_amdgcn_mfma_f32_16x16x32_bf16(
                        af[mi], bf[ni], acc[mi][ni], 0, 0, 0);
        }
        __syncthreads();
    }

    // ---- epilogue ----
    int cj[4], gj[4];
    #pragma unroll
    for (int ni = 0; ni < 4; ni++) {
        int jl = wc * 64 + ni * 16 + (l & 15);
        cj[ni] = clsJ[jl];
        gj[ni] = j0 + jl;
    }
    float ns[4][4];
    #pragma unroll
    for (int mi = 0; mi < 4; mi++) {
        #pragma unroll
        for (int r = 0; r < 4; r++) {
            int il = wr * 64 + mi * 16 + ((l >> 4) << 2) + r;
            int ci = clsI[il];
            int gi = i0 + il;
            float nacc = 0.f;
            #pragma unroll
            for (int ni = 0; ni < 4; ni++) {
                float p = acc[mi][ni][r] * TAU_INV;
                float e = __expf(p);
                if (ci != cj[ni]) {
                    nacc += e;
                } else if (gi != gj[ni]) {
                    int slot = atomicAdd(&poscnt[gi], 1);
                    if (slot < MAXP) posvals[(size_t)gi * MAXP + slot] = p;
                }
            }
            ns[mi][r] = nacc;
        }
    }
    #pragma unroll
    for (int mi = 0; mi < 4; mi++) {
        #pragma unroll
        for (int r = 0; r < 4; r++) {
            float v = ns[mi][r];
            v += __shfl_xor(v, 1);
            v += __shfl_xor(v, 2);
            v += __shfl_xor(v, 4);
            v += __shfl_xor(v, 8);
            if ((l & 15) == 0) {
                int il = wr * 64 + mi * 16 + ((l >> 4) << 2) + r;
                atomicAdd(&negsum[i0 + il], v);
            }
        }
    }
}

// wave per row (lanes = positives); card = poscnt+1 (no histogram needed);
// 64 blocks -> single device-scope atomic per block; done-ticket finalize.
__global__ void k_fin(const float* __restrict__ negsum, const int* __restrict__ poscnt,
                      const float* __restrict__ posvals,
                      float* __restrict__ num, float* __restrict__ den,
                      int* __restrict__ done, float* __restrict__ out)
{
    __shared__ float redN[4], redD[4];
    __shared__ int lastflag;
    int tid = threadIdx.x, w = tid >> 6, l = tid & 63;
    float nacc = 0.f, dacc = 0.f;
    int base = (blockIdx.x * 4 + w) * 16;
    for (int it = 0; it < 16; it++) {
        int row = base + it;
        float S = negsum[row];
        int m = poscnt[row]; if (m > MAXP) m = MAXP;
        float t = 0.f;
        if (l < m) {
            float p = posvals[(size_t)row * MAXP + l];
            t = __logf(__expf(p) + S) - p;
        }
        if (l + 64 < m) {
            float p = posvals[(size_t)row * MAXP + l + 64];
            t += __logf(__expf(p) + S) - p;
        }
        #pragma unroll
        for (int msk = 1; msk < 64; msk <<= 1) t += __shfl_xor(t, msk);
        if (l == 0) {
            float card = (float)(m + 1);
            nacc += t / card;
            dacc += card;
        }
    }
    if (l == 0) { redN[w] = nacc; redD[w] = dacc; }
    __syncthreads();
    if (tid == 0) {
        atomicAdd(num, redN[0] + redN[1] + redN[2] + redN[3]);
        atomicAdd(den, redD[0] + redD[1] + redD[2] + redD[3]);
        __threadfence();
        int d = atomicAdd(done, 1);
        lastflag = (d == (int)gridDim.x - 1) ? 1 : 0;
    }
    __syncthreads();
    if (lastflag && tid == 0) {
        float n = atomicAdd(num, 0.0f);   // coherent device-scope reads
        float dd = atomicAdd(den, 0.0f);
        out[0] = n / dd;
    }
}

extern "C" void kernel_launch(void* const* d_in, const int* in_sizes, int n_in,
                              void* d_out, int out_size, void* d_ws, size_t ws_size,
                              hipStream_t stream) {
    (void)in_sizes; (void)n_in; (void)out_size; (void)ws_size;
    const float* feat = (const float*)d_in[0];
    const int*   tgt  = (const int*)d_in[1];
    float* out = (float*)d_out;
    char* ws = (char*)d_ws;

    unsigned short* fnb = (unsigned short*)(ws + OFF_FNB);
    float* negsum  = (float*)(ws + OFF_NEG);
    int*   poscnt  = (int*)(ws + OFF_CNT);
    float* posvals = (float*)(ws + OFF_PV);
    float* num     = (float*)(ws + OFF_NUM);
    float* den     = (float*)(ws + OFF_DEN);
    int*   done    = (int*)(ws + OFF_DONE);

    k_norm<<<dim3(1024), dim3(256), 0, stream>>>(feat, fnb, (int*)(ws + OFF_NEG));
    k_main<<<dim3(32, 32), dim3(256), 0, stream>>>(fnb, tgt, negsum, poscnt, posvals);
    k_fin<<<dim3(64), dim3(256), 0, stream>>>(negsum, poscnt, posvals, num, den, done, out);
}